// Round 1
// baseline (1517.690 us; speedup 1.0000x reference)
//
#include <hip/hip_runtime.h>
#include <math.h>

// STC loss forward on MI355X.
// One block per batch element (B=32), 320 threads = 5 waves.
// Thread d < 302 owns state d: alpha_new[d] = em[label(d)] + LSE3(alpha[srcs]+w).
// Wave 4 (tid 256..319) is also the emission producer: prefetches input rows
// into a 4-deep register ring (distance 4-6 rows), computes lse via shfl_xor
// butterfly TWO steps ahead into a 4-slot LDS ring, so shuffle/log latency is
// off the per-step critical path. One barrier per step (double-buffered alpha,
// ring-buffered emissions make a single barrier sufficient: reads of iter t
// complete before the barrier; writes of iter t+1 target buffers read at t).

#define T_LEN   2000
#define BATCH   32
#define NCLS    128
#define LTGT    100
#define NSTATES 302          // 3L+2
#define DUMMY   302          // LDS slot permanently NEG_INF (missing arcs)
#define NEG_INF_F (-1e30f)

__global__ void stc_forward(const float* __restrict__ inputs,   // (T,B,C) f32 log-softmax
                            const int*   __restrict__ targets,  // (B,L) i32 in [1,127]
                            float*       __restrict__ scores,   // (B) f32
                            const float logwt)
{
    const int b   = blockIdx.x;
    const int tid = threadIdx.x;

    __shared__ float alpha[2][NSTATES + 2];  // slots 302,303 = dummy NEG_INF
    __shared__ float emit[4][NCLS];          // raw lp rows, 4-deep ring
    __shared__ float lse_s[4];               // lse per ring slot
    __shared__ int   tgt_s[LTGT];

    if (tid < LTGT) tgt_s[tid] = targets[b * LTGT + tid];
    if (tid < NSTATES) {
        alpha[0][tid] = (tid == 0) ? 0.0f : NEG_INF_F;
        alpha[1][tid] = NEG_INF_F;
    } else if (tid < NSTATES + 4) {
        const int i = tid - NSTATES;                 // 0..3
        alpha[i >> 1][NSTATES + (i & 1)] = NEG_INF_F;
    }
    __syncthreads();

    // ---- per-thread arc constants (graph is fixed; targets-dependent parts here)
    int s0 = DUMMY, s1 = DUMMY, s2 = DUMMY, cls = 0;
    float w0 = 0.f, w1 = 0.f, w2 = 0.f;
    bool is_star = false, is_lse = false;
    if (tid < NSTATES) {
        const int d = tid;
        if (d < 2 * LTGT + 1) {                      // lattice states 0..200
            const int k = d >> 1;
            if ((d & 1) == 0) {                      // even: blank
                s0 = d;
                s1 = (d >= 1) ? (d - 1) : DUMMY;
                cls = 0;
            } else {                                 // odd: token tgt[k]
                s0 = d - 1;
                s1 = (k >= 1) ? (d - 2) : DUMMY;     // skip arc
                if (k >= 1) w1 = (tgt_s[k] != tgt_s[k - 1]) ? 0.0f : NEG_INF_F;
                cls = tgt_s[k];
            }
            s2 = 201 + k;                            // star(k) -> lattice
        } else {                                     // star states 201..301
            const int l = d - 201;
            is_star = true;
            s0 = (l >= 1) ? (2 * l - 1) : DUMMY;
            s1 = 2 * l;
            s2 = d;                                  // self loop
            w0 = logwt; w1 = logwt; w2 = logwt;
            if (l < LTGT) cls = tgt_s[l]; else is_lse = true;  // l==L uses lse
        }
    }

    // ---- emission producer state (wave 4)
    const bool emitter = (tid >= 256);
    const int  el = tid & 63;
    const int  c1 = el;                 // class el
    const int  c2 = el + 64;           // class el+64
    float pa[4], pb[4];                 // register ring: row t+2.. prefetched

    if (emitter) {
        #pragma unroll
        for (int u = 0; u < 4; ++u) {   // rows 0..3
            const size_t base = ((size_t)u * BATCH + b) * NCLS;
            pa[u] = inputs[base + c1];
            pb[u] = inputs[base + c2];
        }
        #pragma unroll
        for (int s = 0; s < 2; ++s) {   // prep emissions for t=0,1 (slots 0,1)
            emit[s][c1] = pa[s];
            emit[s][c2] = pb[s];
            float e = __expf(pb[s]);                 // c2 >= 64 >= 1 always
            if (c1 >= 1) e += __expf(pa[s]);         // exclude blank class 0
            #pragma unroll
            for (int off = 32; off >= 1; off >>= 1)
                e += __shfl_xor(e, off, 64);
            if (el == 0) lse_s[s] = __logf(e);
            const size_t base = ((size_t)(4 + s) * BATCH + b) * NCLS;  // reload rows 4,5
            pa[s] = inputs[base + c1];
            pb[s] = inputs[base + c2];
        }
    }
    __syncthreads();

    // ---- main scan: 2000 steps, one barrier per step
    for (int tb = 0; tb < T_LEN; tb += 4) {
        #pragma unroll
        for (int u = 0; u < 4; ++u) {
            const int t  = tb + u;
            const int rb = t & 1;        // alpha read buffer
            const int es = u;            // emit ring slot = t & 3

            if (emitter && (t + 2 < T_LEN)) {        // produce emissions for t+2
                const int ps = (u + 2) & 3;
                const float va = pa[ps], vb = pb[ps];
                emit[ps][c1] = va;
                emit[ps][c2] = vb;
                float e = __expf(vb);
                if (c1 >= 1) e += __expf(va);
                #pragma unroll
                for (int off = 32; off >= 1; off >>= 1)
                    e += __shfl_xor(e, off, 64);
                if (el == 0) lse_s[ps] = __logf(e);
                int rr = t + 6; if (rr > T_LEN - 1) rr = T_LEN - 1;  // prefetch row t+6
                const size_t base = ((size_t)rr * BATCH + b) * NCLS;
                pa[ps] = inputs[base + c1];
                pb[ps] = inputs[base + c2];
            }

            if (tid < NSTATES) {
                const float a0 = alpha[rb][s0] + w0;
                const float a1 = alpha[rb][s1] + w1;
                const float a2 = alpha[rb][s2] + w2;
                const float m  = fmaxf(fmaxf(a0, a1), a2);
                const float z  = __expf(a0 - m) + __expf(a1 - m) + __expf(a2 - m);
                const float lse = lse_s[es];
                const float lp  = emit[es][cls];
                float em;
                if (is_star) {
                    em = is_lse ? lse
                                : (lse + log1pf(1e-7f - __expf(lp - lse)));
                } else {
                    em = lp;             // blank (cls=0) or token lp
                }
                alpha[rb ^ 1][tid] = em + m + __logf(z);
            }
            __syncthreads();
        }
    }

    // final alpha lives in buffer 0 (T even). ACCEPT = {199, 200, 301}
    if (tid == 0) {
        const float a0 = alpha[0][199];
        const float a1 = alpha[0][200];
        const float a2 = alpha[0][301];
        const float m  = fmaxf(fmaxf(a0, a1), a2);
        scores[b] = m + __logf(__expf(a0 - m) + __expf(a1 - m) + __expf(a2 - m));
    }
}

__global__ void stc_finalize(const float* __restrict__ scores,
                             float* __restrict__ out)
{
    float v = 0.0f;
    if (threadIdx.x < BATCH) v = -scores[threadIdx.x] / (float)T_LEN;
    #pragma unroll
    for (int off = 32; off >= 1; off >>= 1)
        v += __shfl_xor(v, off, 64);
    if (threadIdx.x == 0) out[0] = v / (float)BATCH;
}

extern "C" void kernel_launch(void* const* d_in, const int* in_sizes, int n_in,
                              void* d_out, int out_size, void* d_ws, size_t ws_size,
                              hipStream_t stream)
{
    const float* inputs  = (const float*)d_in[0];   // (2000,32,128) f32
    const int*   targets = (const int*)d_in[1];     // (32,100) i32
    float*       out     = (float*)d_out;           // scalar f32
    float*       scores  = (float*)d_ws;            // 32 f32 scratch

    // wt = WLAST + (W0-WLAST)*exp(-NSTEP*ln2/THALF); logwt = log(wt)
    const double wt = 0.1 + 0.9 * exp(-log(2.0) / 10000.0);
    const float logwt = (float)log(wt);

    stc_forward<<<dim3(BATCH), dim3(320), 0, stream>>>(inputs, targets, scores, logwt);
    stc_finalize<<<dim3(1), dim3(64), 0, stream>>>(scores, out);
}

// Round 2
// 524.724 us; speedup vs baseline: 2.8924x; 2.8924x over previous
//
#include <hip/hip_runtime.h>
#include <math.h>

// STC loss forward on MI355X — Round 2.
//
// Round-1 post-mortem: 1815 cy/step. Cause: __syncthreads() compiles to
// "s_waitcnt vmcnt(0) lgkmcnt(0); s_barrier" — the emitter wave's per-step
// global prefetch was drained at EVERY barrier (~900 cy HBM latency/step),
// plus a 6-level shfl butterfly + log1pf library call inside the loop.
//
// Round-2 design:
//  K1 stc_emit (parallel, 16000 blocks): precompute per-(t,b) the 202
//     distinct per-state emissions into em_tab[b][t/4][slot] as float4
//     (4 consecutive timesteps per slot -> one coalesced 16B load / 4 steps).
//     slots: odd state 2k+1 -> k (0..99); star l -> 100+l (l=100 -> 200);
//            blank (all even states) -> 201.
//  K2 stc_scan (32 blocks x 320 thr, latency-bound): thread d owns state d.
//     Emissions arrive via a 4-deep float4 register ring prefetched 3 groups
//     (12 steps) ahead. Barrier = raw "s_waitcnt lgkmcnt(0); s_barrier" asm
//     (memory clobber): orders LDS across waves but leaves global loads in
//     flight -> prefetch actually prefetches. No transcendental beyond
//     3x v_exp + 1x v_log per state per step.

#define T_LEN   2000
#define BATCH   32
#define NCLS    128
#define LTGT    100
#define NSTATES 302          // 3L+2
#define DUMMY   302          // LDS slot permanently NEG_INF (missing arcs)
#define NEG_INF_F (-1e30f)
#define TQ      500          // T_LEN / 4
#define NSLOT   202          // 100 odd + 101 star + 1 blank

// ---------------------------------------------------------------- K1: emissions
__global__ void stc_emit(const float* __restrict__ inputs,   // (T,B,C)
                         const int*   __restrict__ targets,  // (B,L)
                         float4*      __restrict__ em_tab)   // (B,TQ,NSLOT)
{
    const int tq  = blockIdx.x;
    const int b   = blockIdx.y;
    const int tid = threadIdx.x;     // 256 threads = 4 waves; wave j owns row t=4tq+j

    __shared__ float row[4][NCLS];
    __shared__ float lse_s[4];
    __shared__ int   tgt_s[LTGT];

    if (tid < LTGT) tgt_s[tid] = targets[b * LTGT + tid];
    {
        const int j = tid >> 6, c = tid & 63;
        const size_t base = ((size_t)(4 * tq + j) * BATCH + b) * NCLS;
        row[j][c]      = inputs[base + c];
        row[j][c + 64] = inputs[base + c + 64];
    }
    __syncthreads();
    {
        const int j = tid >> 6, lane = tid & 63;
        float e = __expf(row[j][lane + 64]);          // classes 64..127
        if (lane >= 1) e += __expf(row[j][lane]);     // classes 1..63 (skip blank 0)
        #pragma unroll
        for (int off = 32; off >= 1; off >>= 1)
            e += __shfl_xor(e, off, 64);
        if (lane == 0) lse_s[j] = __logf(e);
    }
    __syncthreads();

    if (tid < NSLOT) {
        float v[4];
        #pragma unroll
        for (int j = 0; j < 4; ++j) {
            float o;
            if (tid < LTGT) {                         // odd state k: token lp
                o = row[j][tgt_s[tid]];
            } else if (tid < 200) {                   // star l (l<100): neglse of tgt[l]
                const float lse = lse_s[j];
                o = lse + log1pf(1e-7f - __expf(row[j][tgt_s[tid - 100]] - lse));
            } else if (tid == 200) {                  // star l==L: lse
                o = lse_s[j];
            } else {                                  // blank
                o = row[j][0];
            }
            v[j] = o;
        }
        em_tab[((size_t)b * TQ + tq) * NSLOT + tid] = make_float4(v[0], v[1], v[2], v[3]);
    }
}

// ---------------------------------------------------------------- K2: scan
// Raw barrier: orders LDS (lgkmcnt(0)) across waves, does NOT drain vmcnt,
// so emission prefetch loads stay in flight across barriers.
#define BARRIER() asm volatile("s_waitcnt lgkmcnt(0)\n\ts_barrier" ::: "memory")

__global__ void __launch_bounds__(320)
stc_scan(const float4* __restrict__ em_tab,
         const int*    __restrict__ targets,
         float*        __restrict__ out,
         const float logwt)
{
    const int b   = blockIdx.x;
    const int tid = threadIdx.x;

    __shared__ float alpha[2][NSTATES + 2];  // slots 302,303 = dummy NEG_INF

    if (tid < NSTATES) {
        alpha[0][tid] = (tid == 0) ? 0.0f : NEG_INF_F;
        alpha[1][tid] = NEG_INF_F;
    } else if (tid < NSTATES + 4) {
        const int i = tid - NSTATES;
        alpha[i >> 1][NSTATES + (i & 1)] = NEG_INF_F;
    }

    // per-thread arc constants
    int s0 = DUMMY, s1 = DUMMY, s2 = DUMMY, slot = 0;
    float w0 = 0.f, w1 = 0.f, w2 = 0.f;
    if (tid < NSTATES) {
        const int d = tid;
        if (d < 2 * LTGT + 1) {                      // lattice states 0..200
            const int k = d >> 1;
            if ((d & 1) == 0) {                      // even: blank emission
                s0 = d;
                s1 = (d >= 1) ? (d - 1) : DUMMY;
                slot = 201;
            } else {                                 // odd: token emission
                s0 = d - 1;
                s1 = (k >= 1) ? (d - 2) : DUMMY;     // skip arc
                if (k >= 1)
                    w1 = (targets[b * LTGT + k] != targets[b * LTGT + k - 1])
                         ? 0.0f : NEG_INF_F;
                slot = k;
            }
            s2 = 201 + k;                            // star(k) -> lattice
        } else {                                     // star states 201..301
            const int l = d - 201;
            s0 = (l >= 1) ? (2 * l - 1) : DUMMY;
            s1 = 2 * l;
            s2 = d;                                  // self loop
            w0 = logwt; w1 = logwt; w2 = logwt;
            slot = 100 + l;
        }
    }

    // emission register ring: group g = float4 of timesteps 4g..4g+3
    const size_t base = (size_t)b * TQ * NSLOT + slot;
    float4 rA = em_tab[base + (size_t)0 * NSLOT];
    float4 rB = em_tab[base + (size_t)1 * NSLOT];
    float4 rC = em_tab[base + (size_t)2 * NSLOT];
    float4 rD;

    __syncthreads();   // one-time full barrier after init (vmcnt drain OK here)

#define STEP(RB, EM) do {                                              \
        if (tid < NSTATES) {                                           \
            const float a0 = alpha[RB][s0] + w0;                       \
            const float a1 = alpha[RB][s1] + w1;                       \
            const float a2 = alpha[RB][s2] + w2;                       \
            const float m  = fmaxf(fmaxf(a0, a1), a2);                 \
            const float z  = __expf(a0 - m) + __expf(a1 - m)           \
                           + __expf(a2 - m);                           \
            alpha[(RB) ^ 1][tid] = (EM) + m + __logf(z);               \
        }                                                              \
        BARRIER();                                                     \
    } while (0)

#define GROUP(RUSE, RPRE, G) do {                                      \
        int gp_ = (G) + 3; if (gp_ > TQ - 1) gp_ = TQ - 1;             \
        RPRE = em_tab[base + (size_t)gp_ * NSLOT];                     \
        STEP(0, RUSE.x); STEP(1, RUSE.y);                              \
        STEP(0, RUSE.z); STEP(1, RUSE.w);                              \
    } while (0)

    for (int g = 0; g < TQ; g += 4) {    // 125 iterations, ring rotates by 4
        GROUP(rA, rD, g);
        GROUP(rB, rA, g + 1);
        GROUP(rC, rB, g + 2);
        GROUP(rD, rC, g + 3);
    }
#undef GROUP
#undef STEP

    // final alpha in buffer 0 (last step t=1999 wrote rb^1 = 0).
    // Last BARRIER already ordered the writes; memory clobber forces reload.
    if (tid == 0) {
        const float a0 = alpha[0][199];   // ACCEPT = {2L-1, 2L, 3L+1}
        const float a1 = alpha[0][200];
        const float a2 = alpha[0][301];
        const float m  = fmaxf(fmaxf(a0, a1), a2);
        const float s  = m + __logf(__expf(a0 - m) + __expf(a1 - m) + __expf(a2 - m));
        atomicAdd(out, -s / ((float)T_LEN * (float)BATCH));
    }
}

// ---------------------------------------------------------------- launch
extern "C" void kernel_launch(void* const* d_in, const int* in_sizes, int n_in,
                              void* d_out, int out_size, void* d_ws, size_t ws_size,
                              hipStream_t stream)
{
    const float* inputs  = (const float*)d_in[0];   // (2000,32,128) f32
    const int*   targets = (const int*)d_in[1];     // (32,100) i32
    float*       out     = (float*)d_out;           // scalar f32
    float4*      em_tab  = (float4*)d_ws;           // (B,TQ,NSLOT) float4 = 51.7 MB

    // wt = WLAST + (W0-WLAST)*exp(-NSTEP*ln2/THALF); logwt = log(wt)
    const double wt = 0.1 + 0.9 * exp(-log(2.0) / 10000.0);
    const float logwt = (float)log(wt);

    hipMemsetAsync(out, 0, sizeof(float), stream);
    stc_emit<<<dim3(TQ, BATCH), dim3(256), 0, stream>>>(inputs, targets, em_tab);
    stc_scan<<<dim3(BATCH), dim3(320), 0, stream>>>(em_tab, targets, out, logwt);
}

// Round 7
// 514.460 us; speedup vs baseline: 2.9501x; 1.0199x over previous
//
#include <hip/hip_runtime.h>
#include <math.h>

// STC loss forward on MI355X — Round 7: LOG-domain single-wave scan.
//
// R4-R6 post-mortem: linear-domain + manual per-lane exponents is fragile
// (R4 global-scale underflow -> inf; R5 front-adoption flush -> 4.9e-3;
// R6 ramp/adoption -> transient inf -> NaN via the rescale bit-trick).
// Combine instead the two proven ingredients: R2's log domain (absmax 0.0)
// and R4's single-wave column-parallel structure (no barriers, no LDS).
//
// Column k = states {even 2k (E), odd 2k+1 (O), star k (S)}; all three read
// sources {E, S, p=O_{k-1}} and each state's 3 arcs share one emission:
//   m = max3(E,S,p); eE,eS,eP = exp(.-m);
//   sA = m+log(eE+eS+eP);           E' = sA+blank; S' = sA+star_em;
//   sO = m+log(eE+eS+sk*eP);        O' = sO+tok;
// Exact same grouping as the reference segment-LSE (common emission factors
// out of the max). -1e30 sentinels stay finite: exp(-1e30)=0, empty columns
// have m=-1e30, z=3, and -1e30+1.1 rounds back to -1e30 (ulp(1e30)~1e23).
// zO==0 (skip blocked, E=S empty) clamps to 1e-30 -> phantom mass 69 nats
// below the local max: contributes ~e^-69 relative error. No rescaling.
//
// Lane j owns cols 2j,2j+1; one wave per batch element; cross-lane dep =
// one shfl_up per step; emissions prefetched in an 8-deep register ring.
// K1 writes log tables: tabA[(b*T+t)*50+j] = (ltok2j, ltok2j+1, lstar2j,
// lstar2j+1); tabB[b*T+t] = (lblank, logwt+log(s)).
// lstar_k = logwt + log(s*(1+1e-7) - p_tgt)  ==  logwt + lse +
// log1p(1e-7 - exp(lp-lse)) algebraically. ws = 51,712,000 B (R2 footprint).

#define T_LEN   2000
#define BATCH   32
#define NCLS    128
#define LTGT    100
#define TT      16           // t-rows per emit block
#define RING    8            // emission prefetch depth
#define NEG_INF_F (-1e30f)

// ---------------------------------------------------------------- K1: emissions
__global__ void stc_emit(const float* __restrict__ inputs,   // (T,B,C) log-softmax
                         const int*   __restrict__ targets,  // (B,L)
                         float4*      __restrict__ tabA,
                         float2*      __restrict__ tabB,
                         const float logwt)
{
    const int b   = blockIdx.y;
    const int tid = threadIdx.x;            // 256 threads
    const int r   = tid >> 4, seg = tid & 15;
    const int t   = blockIdx.x * TT + r;

    __shared__ float lps[TT][NCLS];         // raw log-probs
    __shared__ float ssum[TT];              // s = sum_{c>=1} exp(lp)
    __shared__ int   tgt_s[LTGT];

    if (tid < LTGT) tgt_s[tid] = targets[b * LTGT + tid];

    const size_t base = ((size_t)t * BATCH + b) * NCLS + seg * 8;
    const float4 x0 = *(const float4*)(inputs + base);
    const float4 x1 = *(const float4*)(inputs + base + 4);
    *(float4*)&lps[r][seg * 8]     = x0;
    *(float4*)&lps[r][seg * 8 + 4] = x1;

    float ps = __expf(x0.x) + __expf(x0.y) + __expf(x0.z) + __expf(x0.w)
             + __expf(x1.x) + __expf(x1.y) + __expf(x1.z) + __expf(x1.w);
    if (seg == 0) ps -= __expf(x0.x);       // exclude blank class 0
    #pragma unroll
    for (int off = 1; off <= 8; off <<= 1)  // reduce across the 16 segs of row r
        ps += __shfl_xor(ps, off, 64);
    if (seg == 0) ssum[r] = ps;
    __syncthreads();

    const float s = ssum[r];
    const float a = s * (1.0f + 1e-7f);
    const size_t rowA = ((size_t)b * T_LEN + t) * 50;
    #pragma unroll
    for (int j = seg; j < 50; j += 16) {
        const float lt0 = lps[r][tgt_s[2 * j]];
        const float lt1 = lps[r][tgt_s[2 * j + 1]];
        const float st0 = logwt + __logf(a - __expf(lt0));
        const float st1 = logwt + __logf(a - __expf(lt1));
        tabA[rowA + j] = make_float4(lt0, lt1, st0, st1);
    }
    if (seg == 15)
        tabB[(size_t)b * T_LEN + t] = make_float2(lps[r][0], logwt + __logf(s));
}

// ---------------------------------------------------------------- K2: scan
__global__ void __launch_bounds__(64)
stc_scan(const float4* __restrict__ tabA,
         const float2* __restrict__ tabB,
         const int*    __restrict__ targets,
         float*        __restrict__ out)
{
    const int b    = blockIdx.x;
    const int lane = threadIdx.x;           // one wave; lane j owns cols 2j, 2j+1
    const int jc   = (lane < 50) ? lane : 49;   // clamped table slot

    // skip gates (1 = skip arc contributes): col k odd takes p iff k>=1 and
    // tgt[k] != tgt[k-1]
    const int tb0 = b * LTGT;
    float sk0 = 0.0f, sk1 = 0.0f;
    {
        const int c0 = 2 * lane, c1 = 2 * lane + 1;
        if (c0 >= 1 && c0 <= 99)
            sk0 = (targets[tb0 + c0] != targets[tb0 + c0 - 1]) ? 1.0f : 0.0f;
        if (c1 <= 99)
            sk1 = (targets[tb0 + c1] != targets[tb0 + c1 - 1]) ? 1.0f : 0.0f;
    }

    // log-domain state; alpha0: state 0 (even col 0) = 0, rest -1e30
    float E0 = (lane == 0) ? 0.0f : NEG_INF_F;
    float S0 = NEG_INF_F, O0 = NEG_INF_F;
    float E1 = NEG_INF_F, S1 = NEG_INF_F, O1 = NEG_INF_F;
    float p0 = NEG_INF_F;                   // O1 of lane j-1 (log)

    const size_t bT = (size_t)b * T_LEN;
    float4 ra[RING];
    float2 rb[RING];
    #pragma unroll
    for (int u = 0; u < RING; ++u) {
        ra[u] = tabA[(bT + u) * 50 + jc];
        rb[u] = tabB[bT + u];
    }

    // col 1 first: O1n feeds the shfl whose result is needed next step, so
    // its latency hides behind col 0's compute.
#define STEP(v, bb) do {                                               \
        const float st0 = (lane == 50) ? (bb).y : (v).z;               \
        const float m1  = fmaxf(fmaxf(E1, S1), O0);                    \
        const float eE1 = __expf(E1 - m1), eS1 = __expf(S1 - m1);      \
        const float eP1 = __expf(O0 - m1);                             \
        const float z1  = eE1 + eS1 + eP1;                             \
        const float zO1 = fmaxf(fmaf(sk1, eP1, eE1 + eS1), 1e-30f);    \
        const float sA1 = m1 + __logf(z1);                             \
        const float O1n = m1 + __logf(zO1) + (v).y;                    \
        const float pn  = __shfl_up(O1n, 1);                           \
        const float m0  = fmaxf(fmaxf(E0, S0), p0);                    \
        const float eE0 = __expf(E0 - m0), eS0 = __expf(S0 - m0);      \
        const float eP0 = __expf(p0 - m0);                             \
        const float z0  = eE0 + eS0 + eP0;                             \
        const float zO0 = fmaxf(fmaf(sk0, eP0, eE0 + eS0), 1e-30f);    \
        const float sA0 = m0 + __logf(z0);                             \
        O0 = m0 + __logf(zO0) + (v).x;                                 \
        E0 = sA0 + (bb).x;  S0 = sA0 + st0;                            \
        E1 = sA1 + (bb).x;  S1 = sA1 + (v).w;  O1 = O1n;               \
        p0 = (lane == 0) ? NEG_INF_F : pn;                             \
    } while (0)

    for (int tb = 0; tb < T_LEN; tb += RING) {
        #pragma unroll
        for (int u = 0; u < RING; ++u) {
            STEP(ra[u], rb[u]);
            int tp = tb + u + RING; if (tp > T_LEN - 1) tp = T_LEN - 1;
            ra[u] = tabA[(bT + tp) * 50 + jc];
            rb[u] = tabB[bT + tp];
        }
    }
#undef STEP

    // ACCEPT = {odd(99)=lane49.O1, even(100)=lane50.E0, star(100)=lane50.S0}
    const float vO = __shfl(O1, 49, 64);
    const float vE = __shfl(E0, 50, 64);
    const float vS = __shfl(S0, 50, 64);
    if (lane == 0) {
        const float m = fmaxf(fmaxf(vO, vE), vS);
        const float score = m + __logf(__expf(vO - m) + __expf(vE - m)
                                       + __expf(vS - m));
        atomicAdd(out, -score / ((float)T_LEN * (float)BATCH));
    }
}

// ---------------------------------------------------------------- launch
extern "C" void kernel_launch(void* const* d_in, const int* in_sizes, int n_in,
                              void* d_out, int out_size, void* d_ws, size_t ws_size,
                              hipStream_t stream)
{
    const float* inputs  = (const float*)d_in[0];   // (2000,32,128) f32
    const int*   targets = (const int*)d_in[1];     // (32,100) i32
    float*       out     = (float*)d_out;           // scalar f32

    float4* tabA = (float4*)d_ws;                                   // 51.2 MB
    float2* tabB = (float2*)((char*)d_ws + (size_t)BATCH * T_LEN * 50 * 16);

    // wt = WLAST + (W0-WLAST)*exp(-NSTEP*ln2/THALF); logwt = log(wt)
    const double wt = 0.1 + 0.9 * exp(-log(2.0) / 10000.0);
    const float logwt = (float)log(wt);

    (void)hipMemsetAsync(out, 0, sizeof(float), stream);
    stc_emit<<<dim3(T_LEN / TT, BATCH), dim3(256), 0, stream>>>(inputs, targets,
                                                                tabA, tabB, logwt);
    stc_scan<<<dim3(BATCH), dim3(64), 0, stream>>>(tabA, tabB, targets, out);
}